// Round 6
// baseline (252.696 us; speedup 1.0000x reference)
//
#include <hip/hip_runtime.h>

// out = sum(left @ weight) + bias
//   left: (8192,4096) f32   weight: (4096,4096) f32   bias: (1,) f32
// sum(L@W) = dot(colsum(L), rowsum(W)).
// K1 (fused, no dependencies): 1024 blocks stream L -> per-chunk column
// partials; 512 blocks stream W -> row sums. Uniform 128 KB reads/block,
// plain stores only. K2: tiny dot over partials. K3: finisher.

#define DIM 4096

constexpr int L_BLOCKS = 1024;    // 256 row-chunks x 4 col-blocks
constexpr int L_ROWS   = 32;      // rows per chunk (256*32 = 8192)
constexpr int W_BLOCKS = 512;     // 8 rows per block, wave handles 2 rows
constexpr int K1_BLOCKS = L_BLOCKS + W_BLOCKS;

__global__ __launch_bounds__(256) void k_stream(const float* __restrict__ l,
                                                const float* __restrict__ wt,
                                                float* __restrict__ partial, // [256][4096]
                                                float* __restrict__ rowsum)  // [4096]
{
    const int t = threadIdx.x;
    if (blockIdx.x < L_BLOCKS) {
        // ---- column-sum partials of left: 32 rows x 1024 cols ----
        const int lb = blockIdx.x;
        const int chunk = lb >> 2, cb = lb & 3;
        const int col = cb * 1024 + t * 4;
        const float* p = l + (long)chunk * L_ROWS * DIM + col;
        float4 a = make_float4(0.f, 0.f, 0.f, 0.f);
        #pragma unroll 8
        for (int r = 0; r < L_ROWS; ++r) {
            const float4 v = *reinterpret_cast<const float4*>(p + (long)r * DIM);
            a.x += v.x; a.y += v.y; a.z += v.z; a.w += v.w;
        }
        *reinterpret_cast<float4*>(partial + (long)chunk * DIM + col) = a;
    } else {
        // ---- row sums of weight: 8 rows/block, wave w does rows w, w+4 ----
        const int wb = blockIdx.x - L_BLOCKS;
        const int wave = t >> 6, lane = t & 63;
        const int row0 = wb * 8;
        #pragma unroll
        for (int rr = 0; rr < 2; ++rr) {
            const int row = row0 + wave + rr * 4;
            const float* p = wt + (long)row * DIM;
            float4 a = make_float4(0.f, 0.f, 0.f, 0.f);
            #pragma unroll
            for (int i = 0; i < 16; ++i) {
                const float4 v = *reinterpret_cast<const float4*>(p + (i * 64 + lane) * 4);
                a.x += v.x; a.y += v.y; a.z += v.z; a.w += v.w;
            }
            float s = a.x + a.y + a.z + a.w;
            #pragma unroll
            for (int off = 32; off > 0; off >>= 1) s += __shfl_down(s, off);
            if (lane == 0) rowsum[row] = s;
        }
    }
}

// K2: dot( sum_chunks partial[.][c], rowsum[c] ) -> 64 block partials.
// Grid-stride 16384 keeps each thread's column fixed -> rowsum hoisted.
__global__ __launch_bounds__(256) void k_dot(const float* __restrict__ partial,
                                             const float* __restrict__ rowsum,
                                             float* __restrict__ bp)
{
    __shared__ float red[4];
    const int idx0 = blockIdx.x * 256 + threadIdx.x;
    const int total = 256 * DIM;             // 1048576
    const int stride = 64 * 256;             // 16384, multiple of DIM
    float p = 0.f;
    for (int i = idx0; i < total; i += stride) p += partial[i];
    float s = p * rowsum[idx0 & (DIM - 1)];
    #pragma unroll
    for (int off = 32; off > 0; off >>= 1) s += __shfl_down(s, off);
    const int wave = threadIdx.x >> 6, lane = threadIdx.x & 63;
    if (lane == 0) red[wave] = s;
    __syncthreads();
    if (threadIdx.x == 0) bp[blockIdx.x] = red[0] + red[1] + red[2] + red[3];
}

__global__ void k_final(const float* __restrict__ bp,
                        const float* __restrict__ bias,
                        float* __restrict__ out)
{
    const int t = threadIdx.x;   // 64 threads
    float s = bp[t];
    #pragma unroll
    for (int off = 32; off > 0; off >>= 1) s += __shfl_down(s, off);
    if (t == 0) out[0] = s + bias[0];
}

extern "C" void kernel_launch(void* const* d_in, const int* in_sizes, int n_in,
                              void* d_out, int out_size, void* d_ws, size_t ws_size,
                              hipStream_t stream) {
    const float* left   = (const float*)d_in[0];
    const float* weight = (const float*)d_in[1];
    const float* bias   = (const float*)d_in[2];
    float* out = (float*)d_out;

    // ws: partial[256][4096] f32 (4 MB) | rowsum[4096] f32 | bp[64] f32
    float* partial = (float*)d_ws;
    float* rowsum  = partial + 256 * DIM;
    float* bp      = rowsum + DIM;

    k_stream<<<K1_BLOCKS, 256, 0, stream>>>(left, weight, partial, rowsum);
    k_dot   <<<64, 256, 0, stream>>>(partial, rowsum, bp);
    k_final <<<1, 64, 0, stream>>>(bp, bias, out);
}